// Round 10
// baseline (144.821 us; speedup 1.0000x reference)
//
#include <hip/hip_runtime.h>

#define NTOK 16384
#define DIM  512
#define NEXP 8
#define NPAIR 64             // sparse pair buckets: key = lo*8+hi (28 active)
#define PCAP 8192            // per-pair capacity (mean ~585 here; huge headroom)

#define BM 128
#define BN 64                // dual-acc stays at 64 AGPR; grid 1280
#define BK 32                // UNPADDED: required for global_load_lds lane-contiguous dest

typedef __bf16 bf16x8 __attribute__((ext_vector_type(8)));
typedef __bf16 bf16x4 __attribute__((ext_vector_type(4)));
typedef float  f32x4  __attribute__((ext_vector_type(4)));

// async global->LDS 16B per lane. LDS dest MUST be wave-uniform base + lane*16.
__device__ __forceinline__ void async_cp16(const void* g, void* l) {
    __builtin_amdgcn_global_load_lds((const __attribute__((address_space(1))) void*)g,
                                     (__attribute__((address_space(3))) void*)l, 16, 0, 0);
}

// ---------------- K1: fused prep (x-convert pass DELETED: gemm stages fp32 x directly) ----
// blocks [0,2048)    : W [E][k][o] f32 -> Wt tiled [e][kt][o][32] bf16 (transpose+convert)
// blocks [2048,2112) : pair routing (counting sort of TOKENS into 64 pair buckets) + loss slot
__global__ __launch_bounds__(256) void k_prep(const float* __restrict__ W,
                                              __bf16* __restrict__ Wt,
                                              const int* __restrict__ indices,
                                              const float* __restrict__ probs,
                                              int* __restrict__ cnt,
                                              int* __restrict__ tok_arr,
                                              float* __restrict__ plo_arr,
                                              float* __restrict__ phi_arr,
                                              float* __restrict__ out) {
    int b = blockIdx.x, tid = threadIdx.x;
    if (b < 2048) {
        __shared__ __bf16 tile[32][34];             // +2 pad breaks transpose bank conflicts
        int e = b >> 8, rem = b & 255;
        int o0 = (rem >> 4) * 32, k0 = (rem & 15) * 32;
        const float* Wsrc = W + ((size_t)e * DIM + k0) * DIM + o0;
        for (int i = tid; i < 1024; i += 256) {
            int kk = i >> 5, oo = i & 31;           // consecutive tid -> consecutive oo: coalesced
            tile[oo][kk] = (__bf16)Wsrc[(size_t)kk * DIM + oo];
        }
        __syncthreads();
        __bf16* dst = Wt + ((size_t)(e * 16 + (k0 >> 5)) * DIM + o0) * 32;
        for (int i = tid; i < 1024; i += 256) {
            int oo = i >> 5, kk = i & 31;           // row o0+oo, 32 k-elems contiguous
            dst[oo * 32 + kk] = tile[oo][kk];
        }
    } else {
        __shared__ int lcnt[NPAIR], lbase[NPAIR];
        int t = (b - 2048) * 256 + tid;             // token id; 64 blocks cover 16384 tokens
        if (tid < NPAIR) lcnt[tid] = 0;
        __syncthreads();
        int   e0 = indices[2 * t], e1 = indices[2 * t + 1];
        float p0 = probs[2 * t],   p1 = probs[2 * t + 1];
        int lo = min(e0, e1), hi = max(e0, e1);
        float plo = (e0 < e1) ? p0 : p1;
        float phi = (e0 < e1) ? p1 : p0;
        int key = lo * 8 + hi;
        int lr = atomicAdd(&lcnt[key], 1);
        __syncthreads();
        if (tid < NPAIR) lbase[tid] = atomicAdd(&cnt[tid], lcnt[tid]);
        __syncthreads();
        int pos = lbase[key] + lr;
        if (pos < PCAP) {                           // memory-safety clamp (never hit at this dist)
            int q = key * PCAP + pos;
            tok_arr[q] = t; plo_arr[q] = plo; phi_arr[q] = phi;
        }
        if (b == 2048 && tid == 0) out[NTOK * DIM] = 0.0f;   // total_loss
    }
}

// ---------------- K2: pair-grouped GEMM, dual acc, A staged fp32 from x directly -------
// Single K-sweep (16 stages). A tile: 128x32 fp32 (16KB/buf), pair-XOR swizzled; fragments
// converted fp32->bf16 in registers during the compute phase (VALU covers prefetch drain).
// out = pl*acc_lo + ph*acc_hi + pl*b_lo + ph*b_hi.
// grid 1280 = 160 m-slots x 8 n-tiles; 8 n-tiles of an m-slot share blockIdx%8 -> same XCD.
// Exclusive (rows, col-slice) owner: plain fp32 stores, no atomics.
__global__ __launch_bounds__(256) void k_gemm(const float* __restrict__ x,
                                              const __bf16* __restrict__ Wt,
                                              const float* __restrict__ bias,
                                              const int* __restrict__ tok_arr,
                                              const float* __restrict__ plo_arr,
                                              const float* __restrict__ phi_arr,
                                              const int* __restrict__ cnt,
                                              float* __restrict__ out) {
    int p = blockIdx.x;
    int r = p & 7;
    int nt = (p >> 3) & 7;
    int m_slot = (p >> 6) * 8 + r;                  // [0,160)
    int key = -1, m_t = 0, count = 0, total = 0;
    for (int i = 0; i < NPAIR; ++i) {               // uniform scalar prefix decode
        int c = cnt[i];
        int tl = (c + BM - 1) >> 7;
        if (key < 0 && m_slot < total + tl) { key = i; m_t = m_slot - total; count = c; }
        total += tl;
    }
    if (key < 0) return;                            // padding slots (total <= 156)
    if (count > PCAP) count = PCAP;
    int lo = key >> 3, hi = key & 7;
    int m0 = m_t * BM, n0 = nt * BN, tid = threadIdx.x;

    // A fp32 dbuf @0/16K (16KB each), Bl dbuf @32K/36K (4KB), Bh dbuf @40K/44K
    __shared__ __attribute__((aligned(16))) char smem[49152];
    __shared__ int   sTok[BM];
    __shared__ float sPlo[BM], sPhi[BM];

    if (tid < BM) {
        int g = m0 + tid;
        int tk = 0; float a = 0.f, h = 0.f;
        if (g < count) {
            int q = key * PCAP + g;
            tk = tok_arr[q]; a = plo_arr[q]; h = phi_arr[q];
        }
        sTok[tid] = tk;                             // invalid rows alias token 0 (loads safe, store skipped)
        sPlo[tid] = a; sPhi[tid] = h;
    }
    __syncthreads();

    int wid  = tid >> 6, lane = tid & 63;
    int quad = lane >> 4, rr  = lane & 15;
    int wm = (wid >> 1) * 64, wn = (wid & 1) * 32;  // 2x2 waves over 128x64

    // A staging: 128 rows x 32 fp32 = 1024 16B-chunks; thread handles c = tid + j*256.
    // Row = tid>>3 + 32j (row&3 invariant over j). Pair-XOR swizzle: slot pair (tid>>1)&3
    // holds logical pair ((tid>>1)&3) ^ (row&3)  -> 4-way (not 16-way) frag-read conflicts.
    int rA   = tid >> 3;                            // 0..31
    int qc   = ((((tid >> 1) & 3) ^ (rA & 3)) << 1) | (tid & 1);   // logical 4-float chunk
    const float* gA0 = x + (size_t)sTok[rA]      * DIM + qc * 4;
    const float* gA1 = x + (size_t)sTok[rA + 32] * DIM + qc * 4;
    const float* gA2 = x + (size_t)sTok[rA + 64] * DIM + qc * 4;
    const float* gA3 = x + (size_t)sTok[rA + 96] * DIM + qc * 4;
    // B staging: 64 rows x 32k bf16 = 4KB = 256 chunks -> 1/thread; XOR chunk swizzle
    int rB = tid >> 2;
    size_t bOff = (size_t)((rB * 4 + ((tid & 3) ^ (rB & 3))) * 8);
    const __bf16* gBlo = Wt + ((size_t)(lo * 16) * DIM + n0) * 32 + bOff;
    const __bf16* gBhi = Wt + ((size_t)(hi * 16) * DIM + n0) * 32 + bOff;

    f32x4 accL[4][2] = {};
    f32x4 accH[4][2] = {};

    // preload kt=0 into buffer 0
    async_cp16(gA0,  smem + tid * 16);
    async_cp16(gA1,  smem + tid * 16 + 4096);
    async_cp16(gA2,  smem + tid * 16 + 8192);
    async_cp16(gA3,  smem + tid * 16 + 12288);
    async_cp16(gBlo, smem + 32768 + tid * 16);
    async_cp16(gBhi, smem + 40960 + tid * 16);

    #pragma unroll 2
    for (int kt = 0; kt < 16; ++kt) {
        int cur = kt & 1;
        __syncthreads();                            // drains vmcnt(0): buf[cur] ready
        if (kt < 15) {                              // prefetch kt+1 into other buffer
            int ka = (kt + 1) * BK;
            size_t wOff = (size_t)(kt + 1) * DIM * 32;
            int nx = (kt + 1) & 1;
            char* dA = smem + nx * 16384;
            async_cp16(gA0 + ka,    dA + tid * 16);
            async_cp16(gA1 + ka,    dA + tid * 16 + 4096);
            async_cp16(gA2 + ka,    dA + tid * 16 + 8192);
            async_cp16(gA3 + ka,    dA + tid * 16 + 12288);
            async_cp16(gBlo + wOff, smem + 32768 + nx * 4096 + tid * 16);
            async_cp16(gBhi + wOff, smem + 40960 + nx * 4096 + tid * 16);
        }
        const char*   sA  = smem + cur * 16384;
        const __bf16* sBl = (const __bf16*)(smem + 32768 + cur * 4096);
        const __bf16* sBh = (const __bf16*)(smem + 40960 + cur * 4096);
        bf16x8 af[4], bl[2], bh[2];
        #pragma unroll
        for (int i = 0; i < 4; ++i) {               // A frag: fp32 LDS -> bf16 regs
            int row = wm + i * 16 + rr;
            int off = row * 128 + ((quad ^ (row & 3)) * 32);
            f32x4 a0 = *(const f32x4*)(sA + off);
            f32x4 a1 = *(const f32x4*)(sA + off + 16);
            #pragma unroll
            for (int k = 0; k < 4; ++k) { af[i][k] = (__bf16)a0[k]; af[i][4 + k] = (__bf16)a1[k]; }
        }
        int csw = (quad ^ (rr & 3)) * 8;            // B swizzled k-chunk slot (row&3 == rr&3)
        #pragma unroll
        for (int j = 0; j < 2; ++j) {
            bl[j] = *(bf16x8*)&sBl[(wn + j * 16 + rr) * BK + csw];   // B[n=rr][k=quad*8+j]
            bh[j] = *(bf16x8*)&sBh[(wn + j * 16 + rr) * BK + csw];
        }
        #pragma unroll
        for (int i = 0; i < 4; ++i)
            #pragma unroll
            for (int j = 0; j < 2; ++j) {
                accL[i][j] = __builtin_amdgcn_mfma_f32_16x16x32_bf16(af[i], bl[j], accL[i][j], 0, 0, 0);
                accH[i][j] = __builtin_amdgcn_mfma_f32_16x16x32_bf16(af[i], bh[j], accH[i][j], 0, 0, 0);
            }
    }

    // epilogue: C/D layout col=lane&15, row=quad*4+reg.
    // out[tok][col] = pl*accL + ph*accH + pl*b_lo[col] + ph*b_hi[col]  (exclusive owner)
    float blo[2], bhi[2];
    #pragma unroll
    for (int j = 0; j < 2; ++j) {
        blo[j] = bias[lo * DIM + n0 + wn + j * 16 + rr];
        bhi[j] = bias[hi * DIM + n0 + wn + j * 16 + rr];
    }
    #pragma unroll
    for (int i = 0; i < 4; ++i) {
        #pragma unroll
        for (int reg = 0; reg < 4; ++reg) {
            int row = wm + i * 16 + quad * 4 + reg;
            int g = m0 + row;
            if (g >= count) continue;
            int   tk = sTok[row];
            float pl = sPlo[row], ph = sPhi[row];
            float* dst = out + (size_t)tk * DIM + n0 + wn + rr;
            #pragma unroll
            for (int j = 0; j < 2; ++j)
                dst[j * 16] = accL[i][j][reg] * pl + accH[i][j][reg] * ph + pl * blo[j] + ph * bhi[j];
        }
    }
}

extern "C" void kernel_launch(void* const* d_in, const int* in_sizes, int n_in,
                              void* d_out, int out_size, void* d_ws, size_t ws_size,
                              hipStream_t stream) {
    const float* x    = (const float*)d_in[0];   // [N, D]
    const float* prob = (const float*)d_in[1];   // [N, K]
    const int*   idx  = (const int*)d_in[2];     // [N, K]
    const float* W    = (const float*)d_in[3];   // [E, D, D]
    const float* b    = (const float*)d_in[4];   // [E, D]
    float* out = (float*)d_out;                  // [N*D + 1]

    // workspace:
    //   Wt      : E*D*D bf16 (K-tiled [e][kt][o][32]) =  4,194,304 B
    //   cnt     : 64 int (256 B reserved)
    //   tok_arr : 64*PCAP int                         =  2,097,152 B
    //   plo_arr : 64*PCAP float                       =  2,097,152 B
    //   phi_arr : 64*PCAP float                       =  2,097,152 B     total ~10.6 MB
    char* ws = (char*)d_ws;
    __bf16* Wt      = (__bf16*)ws;
    int*    cnt     = (int*)   (ws + 4194304);
    int*    tok_arr = (int*)   (ws + 4194304 + 256);
    float*  plo_arr = (float*) (ws + 4194304 + 256 + 2097152);
    float*  phi_arr = (float*) (ws + 4194304 + 256 + 2 * 2097152);

    (void)hipMemsetAsync(cnt, 0, NPAIR * sizeof(int), stream);
    hipLaunchKernelGGL(k_prep, dim3(2112), dim3(256), 0, stream,
                       W, Wt, idx, prob, cnt, tok_arr, plo_arr, phi_arr, out);
    hipLaunchKernelGGL(k_gemm, dim3(1280), dim3(256), 0, stream,
                       x, Wt, b, tok_arr, plo_arr, phi_arr, cnt, out);
}